// Round 9
// baseline (787.645 us; speedup 1.0000x reference)
//
#include <hip/hip_runtime.h>
#include <hip/hip_bf16.h>

// Problem constants (MoE grouped FFN, uniform groups)
#define NE 32      // experts
#define HD 2048    // hidden
#define ID 1024    // intermediate
#define GT 1024    // tokens per expert (T/E = 32768/32)

#define BK 64

typedef __attribute__((ext_vector_type(8))) __bf16 bf16x8;
typedef __attribute__((ext_vector_type(4))) float  f32x4;

__device__ __forceinline__ __bf16 f2b(float f) { return (__bf16)f; }

__device__ __forceinline__ bf16x8 pack8(const f32x4 a, const f32x4 b) {
  bf16x8 v;
  v[0] = f2b(a[0]); v[1] = f2b(a[1]); v[2] = f2b(a[2]); v[3] = f2b(a[3]);
  v[4] = f2b(b[0]); v[5] = f2b(b[1]); v[6] = f2b(b[2]); v[7] = f2b(b[3]);
  return v;
}

// global_load_lds width=16: LDS dest = wave-uniform base + lane*16 (linear);
// global source is per-lane (pre-swizzled to reproduce the XOR LDS layout).
#define GLDS16(gp, lp)                                                        \
  __builtin_amdgcn_global_load_lds(                                           \
      (const __attribute__((address_space(1))) unsigned int*)(gp),            \
      (__attribute__((address_space(3))) unsigned int*)(lp), 16, 0, 0)

// ---------------------------------------------------------------------------
// Prepass: x (f32, T*H) -> x_bf16 in ws. Memory-bound streaming.
// ---------------------------------------------------------------------------
__global__ __launch_bounds__(256)
void cvt_x_bf16(const float* __restrict__ x, __bf16* __restrict__ xb) {
  size_t i = ((size_t)blockIdx.x * 256 + threadIdx.x) * 8;
  f32x4 a = *reinterpret_cast<const f32x4*>(x + i);
  f32x4 b = *reinterpret_cast<const f32x4*>(x + i + 4);
  *reinterpret_cast<bf16x8*>(xb + i) = pack8(a, b);
}

// ---------------------------------------------------------------------------
// Kernel 1: gate_up = x_e @ w13_e ; h = silu(gate)*up  (bf16 out to ws)
// BM=128, BN=64(g)+64(u). 256 threads = 4 waves (2x2).
// A staged via global_load_lds (dwordx4), source pre-swizzled so the LDS
// layout matches the verified XOR scheme; B (f32 w13) reg-staged with
// in-flight counted vmcnt(8) drain (the 8 B-loads of tile k+2 stay live
// across the barrier — never vmcnt(0) in steady state).
//   A:  As[p][row][(oct ^ (row&7))*8 + j]
//   B:  Bg/Bu[p][row][(oct ^ ((row>>1)&7))*8 + j]
// ---------------------------------------------------------------------------
__global__ __launch_bounds__(256, 2)
void moe_gemm1_swiglu_bA(const __bf16* __restrict__ xb,
                         const float* __restrict__ w13,
                         __bf16* __restrict__ h) {
  __shared__ __bf16 As[2][128][BK];
  __shared__ __bf16 Bg[2][64][BK];
  __shared__ __bf16 Bu[2][64][BK];

  const int t  = threadIdx.x;
  const int e  = blockIdx.z;
  const int m0 = blockIdx.y * 128;
  const int n0 = blockIdx.x * 64;

  const __bf16* xA = xb + (size_t)(e * GT + m0) * HD;
  const float*  wB = w13 + (size_t)e * HD * (2 * ID);

  const int wid = t >> 6, lane = t & 63;
  const int wm = wid >> 1, wn = wid & 1;   // 2x2 waves: 64 rows x 32 cols
  const int fr = lane & 15, fq = lane >> 4;

  // B staging ownership: threads 0-127 stage Bg, 128-255 stage Bu
  const int tb = t & 127;
  const int nq = tb & 15;        // n-quad 0..15 (4 cols over 64)
  const int ko = tb >> 4;        // k-octet 0..7 (8 k-rows)
  const int bcol = (t < 128 ? 0 : ID) + n0 + nq * 4;
  __bf16 (*Bm)[64][BK] = (t < 128) ? Bg : Bu;

  f32x4 accg[4][2];
  f32x4 accu[4][2];
#pragma unroll
  for (int i = 0; i < 4; ++i)
#pragma unroll
    for (int j = 0; j < 2; ++j) { accg[i][j] = 0.f; accu[i][j] = 0.f; }

  f32x4 rb[8];   // B prefetch regs only (A has no reg round-trip)

// A: per wave 4 calls, each covers 8 rows (64 lanes x 16B = 1 KB).
// lane l -> row r0+l/8, slot l&7; source octet = slot ^ (row&7).
#define A_GLDS1(K0, P)                                                        \
  do {                                                                        \
    _Pragma("unroll")                                                         \
    for (int i = 0; i < 4; ++i) {                                             \
      int r0  = wid * 32 + i * 8;                                             \
      int row = r0 + (lane >> 3);                                             \
      int slot = lane & 7;                                                    \
      const __bf16* src =                                                     \
          xA + (size_t)row * HD + (K0) + ((slot ^ (row & 7)) * 8);            \
      GLDS16(src, &As[P][r0][0]);                                             \
    }                                                                         \
  } while (0)

#define LOAD_B1(K0)                                                           \
  do {                                                                        \
    const float* pb = wB + (size_t)((K0) + ko * 8) * (2 * ID) + bcol;         \
    _Pragma("unroll")                                                         \
    for (int j = 0; j < 8; ++j)                                               \
      rb[j] = *reinterpret_cast<const f32x4*>(pb + (size_t)j * (2 * ID));     \
  } while (0)

#define STORE_B1(P)                                                           \
  do {                                                                        \
    _Pragma("unroll")                                                         \
    for (int c = 0; c < 4; ++c) {                                             \
      int row = nq * 4 + c;                                                   \
      int slot = (ko ^ ((row >> 1) & 7)) * 8;                                 \
      bf16x8 v;                                                               \
      _Pragma("unroll")                                                       \
      for (int j = 0; j < 8; ++j) v[j] = f2b(rb[j][c]);                       \
      *reinterpret_cast<bf16x8*>(&Bm[P][row][slot]) = v;                      \
    }                                                                         \
  } while (0)

#define MFMA_HALF1(P, KB)                                                     \
  do {                                                                        \
    bf16x8 af[4], bgf[2], buf2[2];                                            \
    _Pragma("unroll")                                                         \
    for (int mi = 0; mi < 4; ++mi) {                                          \
      int row = wm * 64 + mi * 16 + fr;                                       \
      int oct = (fq + (KB)) ^ (row & 7);                                      \
      af[mi] = *reinterpret_cast<const bf16x8*>(&As[P][row][oct * 8]);        \
    }                                                                         \
    _Pragma("unroll")                                                         \
    for (int ni = 0; ni < 2; ++ni) {                                          \
      int row = wn * 32 + ni * 16 + fr;                                       \
      int oct = (fq + (KB)) ^ ((row >> 1) & 7);                               \
      bgf[ni]  = *reinterpret_cast<const bf16x8*>(&Bg[P][row][oct * 8]);      \
      buf2[ni] = *reinterpret_cast<const bf16x8*>(&Bu[P][row][oct * 8]);      \
    }                                                                         \
    __builtin_amdgcn_s_setprio(1);                                            \
    _Pragma("unroll")                                                         \
    for (int mi = 0; mi < 4; ++mi)                                            \
      _Pragma("unroll")                                                       \
      for (int ni = 0; ni < 2; ++ni) {                                        \
        accg[mi][ni] = __builtin_amdgcn_mfma_f32_16x16x32_bf16(               \
            af[mi], bgf[ni], accg[mi][ni], 0, 0, 0);                          \
        accu[mi][ni] = __builtin_amdgcn_mfma_f32_16x16x32_bf16(               \
            af[mi], buf2[ni], accu[mi][ni], 0, 0, 0);                         \
      }                                                                       \
    __builtin_amdgcn_s_setprio(0);                                            \
  } while (0)

  // prologue: tile0 -> buf0 (A via glds, B via regs), prefetch B(1)
  A_GLDS1(0, 0);
  LOAD_B1(0);
  STORE_B1(0);            // auto vmcnt drains B(0) (and A(0), older)
  LOAD_B1(BK);
  asm volatile("s_waitcnt vmcnt(8) lgkmcnt(0)" ::: "memory");
  __builtin_amdgcn_s_barrier();

  for (int k0 = 0, p = 0; k0 < HD; k0 += BK, p ^= 1) {
    if (k0 + BK < HD) A_GLDS1(k0 + BK, p ^ 1);   // issue earliest
    MFMA_HALF1(p, 0);
    if (k0 + BK < HD) STORE_B1(p ^ 1);           // overlaps MFMA (other buf)
    MFMA_HALF1(p, 4);
    if (k0 + BK < HD) {
      if (k0 + 2 * BK < HD) {
        LOAD_B1(k0 + 2 * BK);
        // retire A-glds(k+1); keep the 8 B-loads(k+2) in flight
        asm volatile("s_waitcnt vmcnt(8) lgkmcnt(0)" ::: "memory");
      } else {
        asm volatile("s_waitcnt vmcnt(0) lgkmcnt(0)" ::: "memory");
      }
      __builtin_amdgcn_s_barrier();
    }
  }
#undef A_GLDS1
#undef LOAD_B1
#undef STORE_B1
#undef MFMA_HALF1

  // ---- epilogue: SwiGLU (in-wave), write h (bf16) ----
#pragma unroll
  for (int mi = 0; mi < 4; ++mi)
#pragma unroll
    for (int ni = 0; ni < 2; ++ni)
#pragma unroll
      for (int j = 0; j < 4; ++j) {
        int row = m0 + wm * 64 + mi * 16 + fq * 4 + j;
        int col = n0 + wn * 32 + ni * 16 + fr;
        float g = accg[mi][ni][j];
        float u = accu[mi][ni][j];
        float s = g / (1.f + __expf(-g));
        h[(size_t)(e * GT + row) * ID + col] = f2b(s * u);
      }
}

// ---------------------------------------------------------------------------
// Kernel 1 fallback (f32 A, R7 verbatim) — used only if ws_size too small.
// ---------------------------------------------------------------------------
__global__ __launch_bounds__(256, 2)
void moe_gemm1_swiglu(const float* __restrict__ x,
                      const float* __restrict__ w13,
                      __bf16* __restrict__ h) {
  __shared__ __bf16 As[2][128][BK];
  __shared__ __bf16 Bg[2][64][BK];
  __shared__ __bf16 Bu[2][64][BK];

  const int t  = threadIdx.x;
  const int e  = blockIdx.z;
  const int m0 = blockIdx.y * 128;
  const int n0 = blockIdx.x * 64;

  const float* xA = x   + (size_t)(e * GT + m0) * HD;
  const float* wB = w13 + (size_t)e * HD * (2 * ID);

  const int wid = t >> 6, lane = t & 63;
  const int wm = wid >> 1, wn = wid & 1;
  const int fr = lane & 15, fq = lane >> 4;

  const int tb = t & 127;
  const int nq = tb & 15;
  const int ko = tb >> 4;
  const int bcol = (t < 128 ? 0 : ID) + n0 + nq * 4;
  __bf16 (*Bm)[64][BK] = (t < 128) ? Bg : Bu;

  f32x4 accg[4][2];
  f32x4 accu[4][2];
#pragma unroll
  for (int i = 0; i < 4; ++i)
#pragma unroll
    for (int j = 0; j < 2; ++j) { accg[i][j] = 0.f; accu[i][j] = 0.f; }

  f32x4 ra[4][2];
  f32x4 rb[8];

#define LOAD_TILE1(K0)                                                         \
  do {                                                                         \
    _Pragma("unroll")                                                          \
    for (int i = 0; i < 4; ++i) {                                              \
      int id = i * 256 + t;                                                    \
      int r = id >> 3, oc = id & 7;                                            \
      const float* src = xA + (size_t)r * HD + (K0) + oc * 8;                  \
      ra[i][0] = *reinterpret_cast<const f32x4*>(src);                         \
      ra[i][1] = *reinterpret_cast<const f32x4*>(src + 4);                     \
    }                                                                          \
    const float* pb = wB + (size_t)((K0) + ko * 8) * (2 * ID) + bcol;          \
    _Pragma("unroll")                                                          \
    for (int j = 0; j < 8; ++j)                                                \
      rb[j] = *reinterpret_cast<const f32x4*>(pb + (size_t)j * (2 * ID));      \
  } while (0)

#define STORE_TILE1(P)                                                         \
  do {                                                                         \
    _Pragma("unroll")                                                          \
    for (int i = 0; i < 4; ++i) {                                              \
      int id = i * 256 + t;                                                    \
      int r = id >> 3, oc = id & 7;                                            \
      *reinterpret_cast<bf16x8*>(&As[P][r][(oc ^ (r & 7)) * 8]) =              \
          pack8(ra[i][0], ra[i][1]);                                           \
    }                                                                          \
    _Pragma("unroll")                                                          \
    for (int c = 0; c < 4; ++c) {                                              \
      int row = nq * 4 + c;                                                    \
      int slot = (ko ^ ((row >> 1) & 7)) * 8;                                  \
      bf16x8 v;                                                                \
      _Pragma("unroll")                                                        \
      for (int j = 0; j < 8; ++j) v[j] = f2b(rb[j][c]);                        \
      *reinterpret_cast<bf16x8*>(&Bm[P][row][slot]) = v;                       \
    }                                                                          \
  } while (0)

#define MFMA_HALF1(P, KB)                                                      \
  do {                                                                         \
    bf16x8 af[4], bgf[2], buf2[2];                                             \
    _Pragma("unroll")                                                          \
    for (int mi = 0; mi < 4; ++mi) {                                           \
      int row = wm * 64 + mi * 16 + fr;                                        \
      int oct = (fq + (KB)) ^ (row & 7);                                       \
      af[mi] = *reinterpret_cast<const bf16x8*>(&As[P][row][oct * 8]);         \
    }                                                                          \
    _Pragma("unroll")                                                          \
    for (int ni = 0; ni < 2; ++ni) {                                           \
      int row = wn * 32 + ni * 16 + fr;                                        \
      int oct = (fq + (KB)) ^ ((row >> 1) & 7);                                \
      bgf[ni]  = *reinterpret_cast<const bf16x8*>(&Bg[P][row][oct * 8]);       \
      buf2[ni] = *reinterpret_cast<const bf16x8*>(&Bu[P][row][oct * 8]);       \
    }                                                                          \
    __builtin_amdgcn_s_setprio(1);                                             \
    _Pragma("unroll")                                                          \
    for (int mi = 0; mi < 4; ++mi)                                             \
      _Pragma("unroll")                                                        \
      for (int ni = 0; ni < 2; ++ni) {                                         \
        accg[mi][ni] = __builtin_amdgcn_mfma_f32_16x16x32_bf16(                \
            af[mi], bgf[ni], accg[mi][ni], 0, 0, 0);                           \
        accu[mi][ni] = __builtin_amdgcn_mfma_f32_16x16x32_bf16(                \
            af[mi], buf2[ni], accu[mi][ni], 0, 0, 0);                          \
      }                                                                        \
    __builtin_amdgcn_s_setprio(0);                                             \
  } while (0)

  LOAD_TILE1(0);
  STORE_TILE1(0);
  LOAD_TILE1(BK);
  asm volatile("s_waitcnt lgkmcnt(0)" ::: "memory");
  __builtin_amdgcn_s_barrier();

  for (int k0 = 0, p = 0; k0 < HD; k0 += BK, p ^= 1) {
    MFMA_HALF1(p, 0);
    if (k0 + BK < HD) STORE_TILE1(p ^ 1);
    MFMA_HALF1(p, 4);
    if (k0 + 2 * BK < HD) LOAD_TILE1(k0 + 2 * BK);
    asm volatile("s_waitcnt lgkmcnt(0)" ::: "memory");
    __builtin_amdgcn_s_barrier();
  }
#undef LOAD_TILE1
#undef STORE_TILE1
#undef MFMA_HALF1

#pragma unroll
  for (int mi = 0; mi < 4; ++mi)
#pragma unroll
    for (int ni = 0; ni < 2; ++ni)
#pragma unroll
      for (int j = 0; j < 4; ++j) {
        int row = m0 + wm * 64 + mi * 16 + fq * 4 + j;
        int col = n0 + wn * 32 + ni * 16 + fr;
        float g = accg[mi][ni][j];
        float u = accu[mi][ni][j];
        float s = g / (1.f + __expf(-g));
        h[(size_t)(e * GT + row) * ID + col] = f2b(s * u);
      }
}

// ---------------------------------------------------------------------------
// Kernel 2: out = h @ w2_e   (h bf16 [T][I], w2 f32 [E][I][H], out f32)
// A via gload_lds (pre-swizzled source), B reg-staged, counted vmcnt(8).
// ---------------------------------------------------------------------------
__global__ __launch_bounds__(256, 2)
void moe_gemm2(const __bf16* __restrict__ h,
               const float* __restrict__ w2,
               float* __restrict__ out) {
  __shared__ __bf16 As[2][128][BK];
  __shared__ __bf16 Bs[2][128][BK];

  const int t  = threadIdx.x;
  const int e  = blockIdx.z;
  const int m0 = blockIdx.y * 128;
  const int n0 = blockIdx.x * 128;

  const __bf16* hA = h  + (size_t)(e * GT + m0) * ID;
  const float*  wB = w2 + (size_t)e * ID * HD;

  const int wid = t >> 6, lane = t & 63;
  const int wm = wid >> 1, wn = wid & 1;
  const int fr = lane & 15, fq = lane >> 4;

  const int nq = t & 31;
  const int ko = t >> 5;

  f32x4 acc[4][4];
#pragma unroll
  for (int i = 0; i < 4; ++i)
#pragma unroll
    for (int j = 0; j < 4; ++j) acc[i][j] = 0.f;

  f32x4 rb[8];

#define A_GLDS2(K0, P)                                                        \
  do {                                                                        \
    _Pragma("unroll")                                                         \
    for (int i = 0; i < 4; ++i) {                                             \
      int r0  = wid * 32 + i * 8;                                             \
      int row = r0 + (lane >> 3);                                             \
      int slot = lane & 7;                                                    \
      const __bf16* src =                                                     \
          hA + (size_t)row * ID + (K0) + ((slot ^ (row & 7)) * 8);            \
      GLDS16(src, &As[P][r0][0]);                                             \
    }                                                                         \
  } while (0)

#define LOAD_B2(K0)                                                           \
  do {                                                                        \
    const float* pg = wB + (size_t)((K0) + ko * 8) * HD + (n0 + nq * 4);      \
    _Pragma("unroll")                                                         \
    for (int j = 0; j < 8; ++j)                                               \
      rb[j] = *reinterpret_cast<const f32x4*>(pg + (size_t)j * HD);           \
  } while (0)

#define STORE_B2(P)                                                           \
  do {                                                                        \
    _Pragma("unroll")                                                         \
    for (int c = 0; c < 4; ++c) {                                             \
      int row = nq * 4 + c;                                                   \
      int slot = (ko ^ ((row >> 1) & 7)) * 8;                                 \
      bf16x8 v;                                                               \
      _Pragma("unroll")                                                       \
      for (int j = 0; j < 8; ++j) v[j] = f2b(rb[j][c]);                       \
      *reinterpret_cast<bf16x8*>(&Bs[P][row][slot]) = v;                      \
    }                                                                         \
  } while (0)

#define MFMA_HALF2(P, KB)                                                     \
  do {                                                                        \
    bf16x8 af[4], bf[4];                                                      \
    _Pragma("unroll")                                                         \
    for (int mi = 0; mi < 4; ++mi) {                                          \
      int row = wm * 64 + mi * 16 + fr;                                       \
      int oct = (fq + (KB)) ^ (row & 7);                                      \
      af[mi] = *reinterpret_cast<const bf16x8*>(&As[P][row][oct * 8]);        \
    }                                                                         \
    _Pragma("unroll")                                                         \
    for (int ni = 0; ni < 4; ++ni) {                                          \
      int row = wn * 64 + ni * 16 + fr;                                       \
      int oct = (fq + (KB)) ^ ((row >> 1) & 7);                               \
      bf[ni] = *reinterpret_cast<const bf16x8*>(&Bs[P][row][oct * 8]);        \
    }                                                                         \
    __builtin_amdgcn_s_setprio(1);                                            \
    _Pragma("unroll")                                                         \
    for (int mi = 0; mi < 4; ++mi)                                            \
      _Pragma("unroll")                                                       \
      for (int ni = 0; ni < 4; ++ni)                                          \
        acc[mi][ni] = __builtin_amdgcn_mfma_f32_16x16x32_bf16(                \
            af[mi], bf[ni], acc[mi][ni], 0, 0, 0);                            \
    __builtin_amdgcn_s_setprio(0);                                            \
  } while (0)

  A_GLDS2(0, 0);
  LOAD_B2(0);
  STORE_B2(0);
  LOAD_B2(BK);
  asm volatile("s_waitcnt vmcnt(8) lgkmcnt(0)" ::: "memory");
  __builtin_amdgcn_s_barrier();

  for (int k0 = 0, p = 0; k0 < ID; k0 += BK, p ^= 1) {
    if (k0 + BK < ID) A_GLDS2(k0 + BK, p ^ 1);
    MFMA_HALF2(p, 0);
    if (k0 + BK < ID) STORE_B2(p ^ 1);
    MFMA_HALF2(p, 4);
    if (k0 + BK < ID) {
      if (k0 + 2 * BK < ID) {
        LOAD_B2(k0 + 2 * BK);
        asm volatile("s_waitcnt vmcnt(8) lgkmcnt(0)" ::: "memory");
      } else {
        asm volatile("s_waitcnt vmcnt(0) lgkmcnt(0)" ::: "memory");
      }
      __builtin_amdgcn_s_barrier();
    }
  }
#undef A_GLDS2
#undef LOAD_B2
#undef STORE_B2
#undef MFMA_HALF2

#pragma unroll
  for (int mi = 0; mi < 4; ++mi)
#pragma unroll
    for (int ni = 0; ni < 4; ++ni)
#pragma unroll
      for (int j = 0; j < 4; ++j) {
        int row = m0 + wm * 64 + mi * 16 + fq * 4 + j;
        int col = n0 + wn * 64 + ni * 16 + fr;
        out[(size_t)(e * GT + row) * HD + col] = acc[mi][ni][j];
      }
}

extern "C" void kernel_launch(void* const* d_in, const int* in_sizes, int n_in,
                              void* d_out, int out_size, void* d_ws, size_t ws_size,
                              hipStream_t stream) {
  const float* x   = (const float*)d_in[0];
  const float* w13 = (const float*)d_in[1];
  const float* w2  = (const float*)d_in[2];
  float* out = (float*)d_out;

  // ws layout: h [0, 64 MiB) ; x_bf16 [64 MiB, 192 MiB)
  const size_t H_BYTES  = (size_t)GT * NE * ID * sizeof(__bf16);   // 64 MiB
  const size_t XB_BYTES = (size_t)GT * NE * HD * sizeof(__bf16);   // 128 MiB
  __bf16* h  = (__bf16*)d_ws;
  __bf16* xb = (__bf16*)((char*)d_ws + H_BYTES);

  if (ws_size >= H_BYTES + XB_BYTES) {
    cvt_x_bf16<<<dim3((GT * NE * (HD / 8)) / 256), dim3(256), 0, stream>>>(x, xb);
    moe_gemm1_swiglu_bA<<<dim3(ID / 64, GT / 128, NE), dim3(256), 0, stream>>>(xb, w13, h);
  } else {
    moe_gemm1_swiglu<<<dim3(ID / 64, GT / 128, NE), dim3(256), 0, stream>>>(x, w13, h);
  }
  moe_gemm2<<<dim3(HD / 128, GT / 128, NE), dim3(256), 0, stream>>>(h, w2, out);
}

// Round 10
// 702.916 us; speedup vs baseline: 1.1205x; 1.1205x over previous
//
#include <hip/hip_runtime.h>
#include <hip/hip_bf16.h>

// Problem constants (MoE grouped FFN, uniform groups)
#define NE 32      // experts
#define HD 2048    // hidden
#define ID 1024    // intermediate
#define GT 1024    // tokens per expert (T/E = 32768/32)

#define BK 64

typedef __attribute__((ext_vector_type(8))) __bf16 bf16x8;
typedef __attribute__((ext_vector_type(4))) float  f32x4;

__device__ __forceinline__ __bf16 f2b(float f) { return (__bf16)f; }

__device__ __forceinline__ bf16x8 pack8(const f32x4 a, const f32x4 b) {
  bf16x8 v;
  v[0] = f2b(a[0]); v[1] = f2b(a[1]); v[2] = f2b(a[2]); v[3] = f2b(a[3]);
  v[4] = f2b(b[0]); v[5] = f2b(b[1]); v[6] = f2b(b[2]); v[7] = f2b(b[3]);
  return v;
}

// ---------------------------------------------------------------------------
// Prepass: x (f32, T*H) -> x_bf16 in ws. Memory-bound streaming.
// ---------------------------------------------------------------------------
__global__ __launch_bounds__(256)
void cvt_x_bf16(const float* __restrict__ x, __bf16* __restrict__ xb) {
  size_t i = ((size_t)blockIdx.x * 256 + threadIdx.x) * 8;
  f32x4 a = *reinterpret_cast<const f32x4*>(x + i);
  f32x4 b = *reinterpret_cast<const f32x4*>(x + i + 4);
  *reinterpret_cast<bf16x8*>(xb + i) = pack8(a, b);
}

// ---------------------------------------------------------------------------
// Kernel 1 (R8 structure, + XCD-chunked remap): gate_up = x_e @ w13_e ;
// h = silu(gate)*up. BM=128, BN=64(g)+64(u). 256 threads = 4 waves (2x2).
// A: bf16 reg-staged (4 loads + 4 swizzled ds_writes, zero cvt).
// B: f32 column-walk + cvt (proven). Single-barrier dbuf loop (R7-proven).
// Remap: 1-D grid 4096 (%8==0 bijective); XCD b&7 gets contiguous 512-work
// chunk = 4 experts; within expert n-major (8 m-blocks sharing a w13 n-panel
// run adjacent on one XCD -> panel L2-resident). R2 measured FETCH -60%.
// ---------------------------------------------------------------------------
__global__ __launch_bounds__(256, 2)
void moe_gemm1_swiglu_bA(const __bf16* __restrict__ xb,
                         const float* __restrict__ w13,
                         __bf16* __restrict__ h) {
  __shared__ __bf16 As[2][128][BK];
  __shared__ __bf16 Bg[2][64][BK];
  __shared__ __bf16 Bu[2][64][BK];

  const int t = threadIdx.x;
  // XCD-chunked bijective remap: expert-major, n-major inner.
  const int bid  = blockIdx.x;
  const int work = (bid & 7) * 512 + (bid >> 3);
  const int e    = work >> 7;          // 128 blocks/expert
  const int rem  = work & 127;
  const int n0   = (rem >> 3) * 64;    // 16 n-tiles, outer
  const int m0   = (rem & 7) * 128;    // 8 m-tiles, inner (panel reuse)

  const __bf16* xA = xb + (size_t)(e * GT + m0) * HD;
  const float*  wB = w13 + (size_t)e * HD * (2 * ID);

  const int wid = t >> 6, lane = t & 63;
  const int wm = wid >> 1, wn = wid & 1;   // 2x2 waves: 64 rows x 32 cols
  const int fr = lane & 15, fq = lane >> 4;

  const int tb = t & 127;
  const int nq = tb & 15;
  const int ko = tb >> 4;
  const int bcol = (t < 128 ? 0 : ID) + n0 + nq * 4;
  __bf16 (*Bm)[64][BK] = (t < 128) ? Bg : Bu;

  f32x4 accg[4][2];
  f32x4 accu[4][2];
#pragma unroll
  for (int i = 0; i < 4; ++i)
#pragma unroll
    for (int j = 0; j < 2; ++j) { accg[i][j] = 0.f; accu[i][j] = 0.f; }

  bf16x8 raa[4];
  f32x4 rb[8];

#define LOAD_TILE1(K0)                                                         \
  do {                                                                         \
    _Pragma("unroll")                                                          \
    for (int i = 0; i < 4; ++i) {                                              \
      int id = i * 256 + t;                                                    \
      int koA = id & 7, m = id >> 3;                                           \
      raa[i] = *reinterpret_cast<const bf16x8*>(xA + (size_t)m * HD + (K0) + koA * 8); \
    }                                                                          \
    const float* pb = wB + (size_t)((K0) + ko * 8) * (2 * ID) + bcol;          \
    _Pragma("unroll")                                                          \
    for (int j = 0; j < 8; ++j)                                                \
      rb[j] = *reinterpret_cast<const f32x4*>(pb + (size_t)j * (2 * ID));      \
  } while (0)

#define STORE_TILE1(P)                                                         \
  do {                                                                         \
    _Pragma("unroll")                                                          \
    for (int i = 0; i < 4; ++i) {                                              \
      int id = i * 256 + t;                                                    \
      int koA = id & 7, m = id >> 3;                                           \
      *reinterpret_cast<bf16x8*>(&As[P][m][(koA ^ (m & 7)) * 8]) = raa[i];     \
    }                                                                          \
    _Pragma("unroll")                                                          \
    for (int c = 0; c < 4; ++c) {                                              \
      int row = nq * 4 + c;                                                    \
      int slot = (ko ^ ((row >> 1) & 7)) * 8;                                  \
      bf16x8 v;                                                                \
      _Pragma("unroll")                                                        \
      for (int j = 0; j < 8; ++j) v[j] = f2b(rb[j][c]);                        \
      *reinterpret_cast<bf16x8*>(&Bm[P][row][slot]) = v;                       \
    }                                                                          \
  } while (0)

#define MFMA_HALF1(P, KB)                                                      \
  do {                                                                         \
    bf16x8 af[4], bgf[2], buf2[2];                                             \
    _Pragma("unroll")                                                          \
    for (int mi = 0; mi < 4; ++mi) {                                           \
      int row = wm * 64 + mi * 16 + fr;                                        \
      int oct = (fq + (KB)) ^ (row & 7);                                       \
      af[mi] = *reinterpret_cast<const bf16x8*>(&As[P][row][oct * 8]);         \
    }                                                                          \
    _Pragma("unroll")                                                          \
    for (int ni = 0; ni < 2; ++ni) {                                           \
      int row = wn * 32 + ni * 16 + fr;                                        \
      int oct = (fq + (KB)) ^ ((row >> 1) & 7);                                \
      bgf[ni]  = *reinterpret_cast<const bf16x8*>(&Bg[P][row][oct * 8]);       \
      buf2[ni] = *reinterpret_cast<const bf16x8*>(&Bu[P][row][oct * 8]);       \
    }                                                                          \
    __builtin_amdgcn_s_setprio(1);                                             \
    _Pragma("unroll")                                                          \
    for (int mi = 0; mi < 4; ++mi)                                             \
      _Pragma("unroll")                                                        \
      for (int ni = 0; ni < 2; ++ni) {                                         \
        accg[mi][ni] = __builtin_amdgcn_mfma_f32_16x16x32_bf16(                \
            af[mi], bgf[ni], accg[mi][ni], 0, 0, 0);                           \
        accu[mi][ni] = __builtin_amdgcn_mfma_f32_16x16x32_bf16(                \
            af[mi], buf2[ni], accu[mi][ni], 0, 0, 0);                          \
      }                                                                        \
    __builtin_amdgcn_s_setprio(0);                                             \
  } while (0)

  LOAD_TILE1(0);
  STORE_TILE1(0);
  LOAD_TILE1(BK);
  asm volatile("s_waitcnt lgkmcnt(0)" ::: "memory");
  __builtin_amdgcn_s_barrier();

  for (int k0 = 0, p = 0; k0 < HD; k0 += BK, p ^= 1) {
    MFMA_HALF1(p, 0);
    if (k0 + BK < HD) STORE_TILE1(p ^ 1);
    MFMA_HALF1(p, 4);
    if (k0 + 2 * BK < HD) LOAD_TILE1(k0 + 2 * BK);
    asm volatile("s_waitcnt lgkmcnt(0)" ::: "memory");
    __builtin_amdgcn_s_barrier();
  }
#undef LOAD_TILE1
#undef STORE_TILE1
#undef MFMA_HALF1

#pragma unroll
  for (int mi = 0; mi < 4; ++mi)
#pragma unroll
    for (int ni = 0; ni < 2; ++ni)
#pragma unroll
      for (int j = 0; j < 4; ++j) {
        int row = m0 + wm * 64 + mi * 16 + fq * 4 + j;
        int col = n0 + wn * 32 + ni * 16 + fr;
        float g = accg[mi][ni][j];
        float u = accu[mi][ni][j];
        float s = g / (1.f + __expf(-g));
        h[(size_t)(e * GT + row) * ID + col] = f2b(s * u);
      }
}

// ---------------------------------------------------------------------------
// Kernel 1 fallback (f32 A, R7 verbatim) — used only if ws_size too small.
// ---------------------------------------------------------------------------
__global__ __launch_bounds__(256, 2)
void moe_gemm1_swiglu(const float* __restrict__ x,
                      const float* __restrict__ w13,
                      __bf16* __restrict__ h) {
  __shared__ __bf16 As[2][128][BK];
  __shared__ __bf16 Bg[2][64][BK];
  __shared__ __bf16 Bu[2][64][BK];

  const int t  = threadIdx.x;
  const int e  = blockIdx.z;
  const int m0 = blockIdx.y * 128;
  const int n0 = blockIdx.x * 64;

  const float* xA = x   + (size_t)(e * GT + m0) * HD;
  const float* wB = w13 + (size_t)e * HD * (2 * ID);

  const int wid = t >> 6, lane = t & 63;
  const int wm = wid >> 1, wn = wid & 1;
  const int fr = lane & 15, fq = lane >> 4;

  const int tb = t & 127;
  const int nq = tb & 15;
  const int ko = tb >> 4;
  const int bcol = (t < 128 ? 0 : ID) + n0 + nq * 4;
  __bf16 (*Bm)[64][BK] = (t < 128) ? Bg : Bu;

  f32x4 accg[4][2];
  f32x4 accu[4][2];
#pragma unroll
  for (int i = 0; i < 4; ++i)
#pragma unroll
    for (int j = 0; j < 2; ++j) { accg[i][j] = 0.f; accu[i][j] = 0.f; }

  f32x4 ra[4][2];
  f32x4 rb[8];

#define LOAD_TILE1(K0)                                                         \
  do {                                                                         \
    _Pragma("unroll")                                                          \
    for (int i = 0; i < 4; ++i) {                                              \
      int id = i * 256 + t;                                                    \
      int r = id >> 3, oc = id & 7;                                            \
      const float* src = xA + (size_t)r * HD + (K0) + oc * 8;                  \
      ra[i][0] = *reinterpret_cast<const f32x4*>(src);                         \
      ra[i][1] = *reinterpret_cast<const f32x4*>(src + 4);                     \
    }                                                                          \
    const float* pb = wB + (size_t)((K0) + ko * 8) * (2 * ID) + bcol;          \
    _Pragma("unroll")                                                          \
    for (int j = 0; j < 8; ++j)                                                \
      rb[j] = *reinterpret_cast<const f32x4*>(pb + (size_t)j * (2 * ID));      \
  } while (0)

#define STORE_TILE1(P)                                                         \
  do {                                                                         \
    _Pragma("unroll")                                                          \
    for (int i = 0; i < 4; ++i) {                                              \
      int id = i * 256 + t;                                                    \
      int r = id >> 3, oc = id & 7;                                            \
      *reinterpret_cast<bf16x8*>(&As[P][r][(oc ^ (r & 7)) * 8]) =              \
          pack8(ra[i][0], ra[i][1]);                                           \
    }                                                                          \
    _Pragma("unroll")                                                          \
    for (int c = 0; c < 4; ++c) {                                              \
      int row = nq * 4 + c;                                                    \
      int slot = (ko ^ ((row >> 1) & 7)) * 8;                                  \
      bf16x8 v;                                                                \
      _Pragma("unroll")                                                        \
      for (int j = 0; j < 8; ++j) v[j] = f2b(rb[j][c]);                        \
      *reinterpret_cast<bf16x8*>(&Bm[P][row][slot]) = v;                       \
    }                                                                          \
  } while (0)

#define MFMA_HALF1(P, KB)                                                      \
  do {                                                                         \
    bf16x8 af[4], bgf[2], buf2[2];                                             \
    _Pragma("unroll")                                                          \
    for (int mi = 0; mi < 4; ++mi) {                                           \
      int row = wm * 64 + mi * 16 + fr;                                        \
      int oct = (fq + (KB)) ^ (row & 7);                                       \
      af[mi] = *reinterpret_cast<const bf16x8*>(&As[P][row][oct * 8]);         \
    }                                                                          \
    _Pragma("unroll")                                                          \
    for (int ni = 0; ni < 2; ++ni) {                                           \
      int row = wn * 32 + ni * 16 + fr;                                        \
      int oct = (fq + (KB)) ^ ((row >> 1) & 7);                                \
      bgf[ni]  = *reinterpret_cast<const bf16x8*>(&Bg[P][row][oct * 8]);       \
      buf2[ni] = *reinterpret_cast<const bf16x8*>(&Bu[P][row][oct * 8]);       \
    }                                                                          \
    __builtin_amdgcn_s_setprio(1);                                             \
    _Pragma("unroll")                                                          \
    for (int mi = 0; mi < 4; ++mi)                                             \
      _Pragma("unroll")                                                        \
      for (int ni = 0; ni < 2; ++ni) {                                         \
        accg[mi][ni] = __builtin_amdgcn_mfma_f32_16x16x32_bf16(                \
            af[mi], bgf[ni], accg[mi][ni], 0, 0, 0);                           \
        accu[mi][ni] = __builtin_amdgcn_mfma_f32_16x16x32_bf16(                \
            af[mi], buf2[ni], accu[mi][ni], 0, 0, 0);                          \
      }                                                                        \
    __builtin_amdgcn_s_setprio(0);                                             \
  } while (0)

  LOAD_TILE1(0);
  STORE_TILE1(0);
  LOAD_TILE1(BK);
  asm volatile("s_waitcnt lgkmcnt(0)" ::: "memory");
  __builtin_amdgcn_s_barrier();

  for (int k0 = 0, p = 0; k0 < HD; k0 += BK, p ^= 1) {
    MFMA_HALF1(p, 0);
    if (k0 + BK < HD) STORE_TILE1(p ^ 1);
    MFMA_HALF1(p, 4);
    if (k0 + 2 * BK < HD) LOAD_TILE1(k0 + 2 * BK);
    asm volatile("s_waitcnt lgkmcnt(0)" ::: "memory");
    __builtin_amdgcn_s_barrier();
  }
#undef LOAD_TILE1
#undef STORE_TILE1
#undef MFMA_HALF1

#pragma unroll
  for (int mi = 0; mi < 4; ++mi)
#pragma unroll
    for (int ni = 0; ni < 2; ++ni)
#pragma unroll
      for (int j = 0; j < 4; ++j) {
        int row = m0 + wm * 64 + mi * 16 + fq * 4 + j;
        int col = n0 + wn * 32 + ni * 16 + fr;
        float g = accg[mi][ni][j];
        float u = accu[mi][ni][j];
        float s = g / (1.f + __expf(-g));
        h[(size_t)(e * GT + row) * ID + col] = f2b(s * u);
      }
}

// ---------------------------------------------------------------------------
// Kernel 2 (R7 structure, + XCD-chunked remap): out = h @ w2_e
// 1-D grid 4096 = 32 experts x 16 n x 8 m; same remap as gemm1.
// ---------------------------------------------------------------------------
__global__ __launch_bounds__(256, 2)
void moe_gemm2(const __bf16* __restrict__ h,
               const float* __restrict__ w2,
               float* __restrict__ out) {
  __shared__ __bf16 As[2][128][BK];
  __shared__ __bf16 Bs[2][128][BK];

  const int t = threadIdx.x;
  const int bid  = blockIdx.x;
  const int work = (bid & 7) * 512 + (bid >> 3);
  const int e    = work >> 7;
  const int rem  = work & 127;
  const int n0   = (rem >> 3) * 128;   // 16 n-tiles, outer
  const int m0   = (rem & 7) * 128;    // 8 m-tiles, inner

  const __bf16* hA = h  + (size_t)(e * GT + m0) * ID;
  const float*  wB = w2 + (size_t)e * ID * HD;

  const int wid = t >> 6, lane = t & 63;
  const int wm = wid >> 1, wn = wid & 1;
  const int fr = lane & 15, fq = lane >> 4;

  const int nq = t & 31;
  const int ko = t >> 5;

  f32x4 acc[4][4];
#pragma unroll
  for (int i = 0; i < 4; ++i)
#pragma unroll
    for (int j = 0; j < 4; ++j) acc[i][j] = 0.f;

  bf16x8 raa[4];
  f32x4 rb[8];

#define LOAD_TILE2(K0)                                                         \
  do {                                                                         \
    _Pragma("unroll")                                                          \
    for (int i = 0; i < 4; ++i) {                                              \
      int id = i * 256 + t;                                                    \
      int koA = id & 7, m = id >> 3;                                           \
      raa[i] = *reinterpret_cast<const bf16x8*>(hA + (size_t)m * ID + (K0) + koA * 8); \
    }                                                                          \
    const float* pg = wB + (size_t)((K0) + ko * 8) * HD + (n0 + nq * 4);       \
    _Pragma("unroll")                                                          \
    for (int j = 0; j < 8; ++j)                                                \
      rb[j] = *reinterpret_cast<const f32x4*>(pg + (size_t)j * HD);            \
  } while (0)

#define STORE_TILE2(P)                                                         \
  do {                                                                         \
    _Pragma("unroll")                                                          \
    for (int i = 0; i < 4; ++i) {                                              \
      int id = i * 256 + t;                                                    \
      int koA = id & 7, m = id >> 3;                                           \
      *reinterpret_cast<bf16x8*>(&As[P][m][(koA ^ (m & 7)) * 8]) = raa[i];     \
    }                                                                          \
    _Pragma("unroll")                                                          \
    for (int c = 0; c < 4; ++c) {                                              \
      int row = nq * 4 + c;                                                    \
      int slot = (ko ^ ((row >> 1) & 7)) * 8;                                  \
      bf16x8 v;                                                                \
      _Pragma("unroll")                                                        \
      for (int j = 0; j < 8; ++j) v[j] = f2b(rb[j][c]);                        \
      *reinterpret_cast<bf16x8*>(&Bs[P][row][slot]) = v;                       \
    }                                                                          \
  } while (0)

#define MFMA_HALF2(P, KB)                                                      \
  do {                                                                         \
    bf16x8 af[4], bf[4];                                                       \
    _Pragma("unroll")                                                          \
    for (int mi = 0; mi < 4; ++mi) {                                           \
      int row = wm * 64 + mi * 16 + fr;                                        \
      int oct = (fq + (KB)) ^ (row & 7);                                       \
      af[mi] = *reinterpret_cast<const bf16x8*>(&As[P][row][oct * 8]);         \
    }                                                                          \
    _Pragma("unroll")                                                          \
    for (int ni = 0; ni < 4; ++ni) {                                           \
      int row = wn * 64 + ni * 16 + fr;                                        \
      int oct = (fq + (KB)) ^ ((row >> 1) & 7);                                \
      bf[ni] = *reinterpret_cast<const bf16x8*>(&Bs[P][row][oct * 8]);         \
    }                                                                          \
    __builtin_amdgcn_s_setprio(1);                                             \
    _Pragma("unroll")                                                          \
    for (int mi = 0; mi < 4; ++mi)                                             \
      _Pragma("unroll")                                                        \
      for (int ni = 0; ni < 4; ++ni)                                           \
        acc[mi][ni] = __builtin_amdgcn_mfma_f32_16x16x32_bf16(                 \
            af[mi], bf[ni], acc[mi][ni], 0, 0, 0);                             \
    __builtin_amdgcn_s_setprio(0);                                             \
  } while (0)

  LOAD_TILE2(0);
  STORE_TILE2(0);
  LOAD_TILE2(BK);
  asm volatile("s_waitcnt lgkmcnt(0)" ::: "memory");
  __builtin_amdgcn_s_barrier();

  for (int k0 = 0, p = 0; k0 < ID; k0 += BK, p ^= 1) {
    MFMA_HALF2(p, 0);
    if (k0 + BK < ID) STORE_TILE2(p ^ 1);
    MFMA_HALF2(p, 4);
    if (k0 + 2 * BK < ID) LOAD_TILE2(k0 + 2 * BK);
    asm volatile("s_waitcnt lgkmcnt(0)" ::: "memory");
    __builtin_amdgcn_s_barrier();
  }
#undef LOAD_TILE2
#undef STORE_TILE2
#undef MFMA_HALF2

#pragma unroll
  for (int mi = 0; mi < 4; ++mi)
#pragma unroll
    for (int ni = 0; ni < 4; ++ni)
#pragma unroll
      for (int j = 0; j < 4; ++j) {
        int row = m0 + wm * 64 + mi * 16 + fq * 4 + j;
        int col = n0 + wn * 64 + ni * 16 + fr;
        out[(size_t)(e * GT + row) * HD + col] = acc[mi][ni][j];
      }
}

extern "C" void kernel_launch(void* const* d_in, const int* in_sizes, int n_in,
                              void* d_out, int out_size, void* d_ws, size_t ws_size,
                              hipStream_t stream) {
  const float* x   = (const float*)d_in[0];
  const float* w13 = (const float*)d_in[1];
  const float* w2  = (const float*)d_in[2];
  float* out = (float*)d_out;

  // ws layout: h [0, 64 MiB) ; x_bf16 [64 MiB, 192 MiB)
  const size_t H_BYTES  = (size_t)GT * NE * ID * sizeof(__bf16);   // 64 MiB
  const size_t XB_BYTES = (size_t)GT * NE * HD * sizeof(__bf16);   // 128 MiB
  __bf16* h  = (__bf16*)d_ws;
  __bf16* xb = (__bf16*)((char*)d_ws + H_BYTES);

  if (ws_size >= H_BYTES + XB_BYTES) {
    cvt_x_bf16<<<dim3((GT * NE * (HD / 8)) / 256), dim3(256), 0, stream>>>(x, xb);
    moe_gemm1_swiglu_bA<<<dim3(4096), dim3(256), 0, stream>>>(xb, w13, h);
  } else {
    moe_gemm1_swiglu<<<dim3(ID / 64, GT / 128, NE), dim3(256), 0, stream>>>(x, w13, h);
  }
  moe_gemm2<<<dim3(4096), dim3(256), 0, stream>>>(h, w2, out);
}

// Round 11
// 560.086 us; speedup vs baseline: 1.4063x; 1.2550x over previous
//
#include <hip/hip_runtime.h>
#include <hip/hip_bf16.h>

// Problem constants (MoE grouped FFN, uniform groups)
#define NE 32      // experts
#define HD 2048    // hidden
#define ID 1024    // intermediate
#define GT 1024    // tokens per expert (T/E = 32768/32)

#define BK 64

typedef __attribute__((ext_vector_type(8))) __bf16 bf16x8;
typedef __attribute__((ext_vector_type(4))) float  f32x4;

__device__ __forceinline__ __bf16 f2b(float f) { return (__bf16)f; }

__device__ __forceinline__ bf16x8 pack8(const f32x4 a, const f32x4 b) {
  bf16x8 v;
  v[0] = f2b(a[0]); v[1] = f2b(a[1]); v[2] = f2b(a[2]); v[3] = f2b(a[3]);
  v[4] = f2b(b[0]); v[5] = f2b(b[1]); v[6] = f2b(b[2]); v[7] = f2b(b[3]);
  return v;
}

// ---------------------------------------------------------------------------
// Prepass: x (f32, T*H) -> x_bf16 in ws. Memory-bound streaming.
// ---------------------------------------------------------------------------
__global__ __launch_bounds__(256)
void cvt_x_bf16(const float* __restrict__ x, __bf16* __restrict__ xb) {
  size_t i = ((size_t)blockIdx.x * 256 + threadIdx.x) * 8;
  f32x4 a = *reinterpret_cast<const f32x4*>(x + i);
  f32x4 b = *reinterpret_cast<const f32x4*>(x + i + 4);
  *reinterpret_cast<bf16x8*>(xb + i) = pack8(a, b);
}

// ---------------------------------------------------------------------------
// Kernel 1 (256-row tile): gate_up = x_e @ w13_e ; h = silu(gate)*up
// BM=256, BNh=128 (gate & up each 128 wide). 512 threads = 8 waves (2x4);
// wave owns 128 rows x 32 cols of BOTH gate and up (acc = 128 f32).
// DS bytes/FLOP -33% vs 128-tile (writes 64KB + reads 192KB per 8.4 MFLOP).
// Mechanics carried verbatim from R8/R10 (all counter-verified): bf16-A
// reg-staging, f32-B column-walk+cvt, XOR swizzles, single-barrier dbuf,
// setprio, lgkm-only barrier, XCD-chunked remap.
// LDS: As 2x256x64 + Bg/Bu 2x128x64 each, bf16 = 128 KB (1 block/CU).
// ---------------------------------------------------------------------------
__global__ __launch_bounds__(512, 2)
void moe_gemm1_swiglu_bA(const __bf16* __restrict__ xb,
                         const float* __restrict__ w13,
                         __bf16* __restrict__ h) {
  __shared__ __bf16 As[2][256][BK];
  __shared__ __bf16 Bg[2][128][BK];
  __shared__ __bf16 Bu[2][128][BK];

  const int t = threadIdx.x;
  // XCD-chunked bijective remap (1024 blocks, %8==0): 4 experts/XCD,
  // m-inner so 4 m-blocks sharing a w13 n-panel run adjacent on one XCD.
  const int bid  = blockIdx.x;
  const int work = (bid & 7) * 128 + (bid >> 3);
  const int e    = work >> 5;          // 32 blocks/expert
  const int rem  = work & 31;
  const int n0   = (rem >> 2) * 128;   // 8 n-tiles, outer
  const int m0   = (rem & 3) * 256;    // 4 m-tiles, inner

  const __bf16* xA = xb + (size_t)(e * GT + m0) * HD;
  const float*  wB = w13 + (size_t)e * HD * (2 * ID);

  const int wid = t >> 6, lane = t & 63;
  const int wm = wid >> 2, wn = wid & 3;   // 2x4 waves: 128 rows x 32 cols
  const int fr = lane & 15, fq = lane >> 4;

  // B staging: threads 0-255 stage Bg, 256-511 stage Bu (wave-uniform split)
  const int tb = t & 255;
  const int nq = tb & 31;        // n-quad 0..31 (4 cols over 128)
  const int ko = tb >> 5;        // k-octet 0..7
  const int bcol = (t < 256 ? 0 : ID) + n0 + nq * 4;
  __bf16 (*Bm)[128][BK] = (t < 256) ? Bg : Bu;

  f32x4 accg[8][2];
  f32x4 accu[8][2];
#pragma unroll
  for (int i = 0; i < 8; ++i)
#pragma unroll
    for (int j = 0; j < 2; ++j) { accg[i][j] = 0.f; accu[i][j] = 0.f; }

  bf16x8 raa[4];   // A prefetch (16 VGPR)
  f32x4 rb[8];     // B prefetch (32 VGPR)

#define LOAD_TILE1(K0)                                                         \
  do {                                                                         \
    _Pragma("unroll")                                                          \
    for (int i = 0; i < 4; ++i) {                                              \
      int id = i * 512 + t;                                                    \
      int koA = id & 7, m = id >> 3;                                           \
      raa[i] = *reinterpret_cast<const bf16x8*>(xA + (size_t)m * HD + (K0) + koA * 8); \
    }                                                                          \
    const float* pb = wB + (size_t)((K0) + ko * 8) * (2 * ID) + bcol;          \
    _Pragma("unroll")                                                          \
    for (int j = 0; j < 8; ++j)                                                \
      rb[j] = *reinterpret_cast<const f32x4*>(pb + (size_t)j * (2 * ID));      \
  } while (0)

#define STORE_TILE1(P)                                                         \
  do {                                                                         \
    _Pragma("unroll")                                                          \
    for (int i = 0; i < 4; ++i) {                                              \
      int id = i * 512 + t;                                                    \
      int koA = id & 7, m = id >> 3;                                           \
      *reinterpret_cast<bf16x8*>(&As[P][m][(koA ^ (m & 7)) * 8]) = raa[i];     \
    }                                                                          \
    _Pragma("unroll")                                                          \
    for (int c = 0; c < 4; ++c) {                                              \
      int row = nq * 4 + c;                                                    \
      int slot = (ko ^ ((row >> 1) & 7)) * 8;                                  \
      bf16x8 v;                                                                \
      _Pragma("unroll")                                                        \
      for (int j = 0; j < 8; ++j) v[j] = f2b(rb[j][c]);                        \
      *reinterpret_cast<bf16x8*>(&Bm[P][row][slot]) = v;                       \
    }                                                                          \
  } while (0)

#define MFMA_HALF1(P, KB)                                                      \
  do {                                                                         \
    bf16x8 af[8], bgf[2], buf2[2];                                             \
    _Pragma("unroll")                                                          \
    for (int mi = 0; mi < 8; ++mi) {                                           \
      int row = wm * 128 + mi * 16 + fr;                                       \
      int oct = (fq + (KB)) ^ (row & 7);                                       \
      af[mi] = *reinterpret_cast<const bf16x8*>(&As[P][row][oct * 8]);         \
    }                                                                          \
    _Pragma("unroll")                                                          \
    for (int ni = 0; ni < 2; ++ni) {                                           \
      int row = wn * 32 + ni * 16 + fr;                                        \
      int oct = (fq + (KB)) ^ ((row >> 1) & 7);                                \
      bgf[ni]  = *reinterpret_cast<const bf16x8*>(&Bg[P][row][oct * 8]);       \
      buf2[ni] = *reinterpret_cast<const bf16x8*>(&Bu[P][row][oct * 8]);       \
    }                                                                          \
    __builtin_amdgcn_s_setprio(1);                                             \
    _Pragma("unroll")                                                          \
    for (int mi = 0; mi < 8; ++mi)                                             \
      _Pragma("unroll")                                                        \
      for (int ni = 0; ni < 2; ++ni) {                                         \
        accg[mi][ni] = __builtin_amdgcn_mfma_f32_16x16x32_bf16(                \
            af[mi], bgf[ni], accg[mi][ni], 0, 0, 0);                           \
        accu[mi][ni] = __builtin_amdgcn_mfma_f32_16x16x32_bf16(                \
            af[mi], buf2[ni], accu[mi][ni], 0, 0, 0);                          \
      }                                                                        \
    __builtin_amdgcn_s_setprio(0);                                             \
  } while (0)

  LOAD_TILE1(0);
  STORE_TILE1(0);
  LOAD_TILE1(BK);
  asm volatile("s_waitcnt lgkmcnt(0)" ::: "memory");
  __builtin_amdgcn_s_barrier();

  for (int k0 = 0, p = 0; k0 < HD; k0 += BK, p ^= 1) {
    MFMA_HALF1(p, 0);
    if (k0 + BK < HD) STORE_TILE1(p ^ 1);      // overlaps MFMA (other buffer)
    MFMA_HALF1(p, 4);
    if (k0 + 2 * BK < HD) LOAD_TILE1(k0 + 2 * BK);
    asm volatile("s_waitcnt lgkmcnt(0)" ::: "memory");
    __builtin_amdgcn_s_barrier();
  }
#undef LOAD_TILE1
#undef STORE_TILE1
#undef MFMA_HALF1

  // ---- epilogue: SwiGLU (in-wave), write h (bf16) ----
#pragma unroll
  for (int mi = 0; mi < 8; ++mi)
#pragma unroll
    for (int ni = 0; ni < 2; ++ni)
#pragma unroll
      for (int j = 0; j < 4; ++j) {
        int row = m0 + wm * 128 + mi * 16 + fq * 4 + j;
        int col = n0 + wn * 32 + ni * 16 + fr;
        float g = accg[mi][ni][j];
        float u = accu[mi][ni][j];
        float s = g / (1.f + __expf(-g));
        h[(size_t)(e * GT + row) * ID + col] = f2b(s * u);
      }
}

// ---------------------------------------------------------------------------
// Kernel 1 fallback (f32 A, R7 verbatim) — used only if ws_size too small.
// ---------------------------------------------------------------------------
__global__ __launch_bounds__(256, 2)
void moe_gemm1_swiglu(const float* __restrict__ x,
                      const float* __restrict__ w13,
                      __bf16* __restrict__ h) {
  __shared__ __bf16 As[2][128][BK];
  __shared__ __bf16 Bg[2][64][BK];
  __shared__ __bf16 Bu[2][64][BK];

  const int t  = threadIdx.x;
  const int e  = blockIdx.z;
  const int m0 = blockIdx.y * 128;
  const int n0 = blockIdx.x * 64;

  const float* xA = x   + (size_t)(e * GT + m0) * HD;
  const float* wB = w13 + (size_t)e * HD * (2 * ID);

  const int wid = t >> 6, lane = t & 63;
  const int wm = wid >> 1, wn = wid & 1;
  const int fr = lane & 15, fq = lane >> 4;

  const int tb = t & 127;
  const int nq = tb & 15;
  const int ko = tb >> 4;
  const int bcol = (t < 128 ? 0 : ID) + n0 + nq * 4;
  __bf16 (*Bm)[64][BK] = (t < 128) ? Bg : Bu;

  f32x4 accg[4][2];
  f32x4 accu[4][2];
#pragma unroll
  for (int i = 0; i < 4; ++i)
#pragma unroll
    for (int j = 0; j < 2; ++j) { accg[i][j] = 0.f; accu[i][j] = 0.f; }

  f32x4 ra[4][2];
  f32x4 rb[8];

#define LOAD_TILE1(K0)                                                         \
  do {                                                                         \
    _Pragma("unroll")                                                          \
    for (int i = 0; i < 4; ++i) {                                              \
      int id = i * 256 + t;                                                    \
      int r = id >> 3, oc = id & 7;                                            \
      const float* src = xA + (size_t)r * HD + (K0) + oc * 8;                  \
      ra[i][0] = *reinterpret_cast<const f32x4*>(src);                         \
      ra[i][1] = *reinterpret_cast<const f32x4*>(src + 4);                     \
    }                                                                          \
    const float* pb = wB + (size_t)((K0) + ko * 8) * (2 * ID) + bcol;          \
    _Pragma("unroll")                                                          \
    for (int j = 0; j < 8; ++j)                                                \
      rb[j] = *reinterpret_cast<const f32x4*>(pb + (size_t)j * (2 * ID));      \
  } while (0)

#define STORE_TILE1(P)                                                         \
  do {                                                                         \
    _Pragma("unroll")                                                          \
    for (int i = 0; i < 4; ++i) {                                              \
      int id = i * 256 + t;                                                    \
      int r = id >> 3, oc = id & 7;                                            \
      *reinterpret_cast<bf16x8*>(&As[P][r][(oc ^ (r & 7)) * 8]) =              \
          pack8(ra[i][0], ra[i][1]);                                           \
    }                                                                          \
    _Pragma("unroll")                                                          \
    for (int c = 0; c < 4; ++c) {                                              \
      int row = nq * 4 + c;                                                    \
      int slot = (ko ^ ((row >> 1) & 7)) * 8;                                  \
      bf16x8 v;                                                                \
      _Pragma("unroll")                                                        \
      for (int j = 0; j < 8; ++j) v[j] = f2b(rb[j][c]);                        \
      *reinterpret_cast<bf16x8*>(&Bm[P][row][slot]) = v;                       \
    }                                                                          \
  } while (0)

#define MFMA_HALF1(P, KB)                                                      \
  do {                                                                         \
    bf16x8 af[4], bgf[2], buf2[2];                                             \
    _Pragma("unroll")                                                          \
    for (int mi = 0; mi < 4; ++mi) {                                           \
      int row = wm * 64 + mi * 16 + fr;                                        \
      int oct = (fq + (KB)) ^ (row & 7);                                       \
      af[mi] = *reinterpret_cast<const bf16x8*>(&As[P][row][oct * 8]);         \
    }                                                                          \
    _Pragma("unroll")                                                          \
    for (int ni = 0; ni < 2; ++ni) {                                           \
      int row = wn * 32 + ni * 16 + fr;                                        \
      int oct = (fq + (KB)) ^ ((row >> 1) & 7);                                \
      bgf[ni]  = *reinterpret_cast<const bf16x8*>(&Bg[P][row][oct * 8]);       \
      buf2[ni] = *reinterpret_cast<const bf16x8*>(&Bu[P][row][oct * 8]);       \
    }                                                                          \
    __builtin_amdgcn_s_setprio(1);                                             \
    _Pragma("unroll")                                                          \
    for (int mi = 0; mi < 4; ++mi)                                             \
      _Pragma("unroll")                                                        \
      for (int ni = 0; ni < 2; ++ni) {                                         \
        accg[mi][ni] = __builtin_amdgcn_mfma_f32_16x16x32_bf16(                \
            af[mi], bgf[ni], accg[mi][ni], 0, 0, 0);                           \
        accu[mi][ni] = __builtin_amdgcn_mfma_f32_16x16x32_bf16(                \
            af[mi], buf2[ni], accu[mi][ni], 0, 0, 0);                          \
      }                                                                        \
    __builtin_amdgcn_s_setprio(0);                                             \
  } while (0)

  LOAD_TILE1(0);
  STORE_TILE1(0);
  LOAD_TILE1(BK);
  asm volatile("s_waitcnt lgkmcnt(0)" ::: "memory");
  __builtin_amdgcn_s_barrier();

  for (int k0 = 0, p = 0; k0 < HD; k0 += BK, p ^= 1) {
    MFMA_HALF1(p, 0);
    if (k0 + BK < HD) STORE_TILE1(p ^ 1);
    MFMA_HALF1(p, 4);
    if (k0 + 2 * BK < HD) LOAD_TILE1(k0 + 2 * BK);
    asm volatile("s_waitcnt lgkmcnt(0)" ::: "memory");
    __builtin_amdgcn_s_barrier();
  }
#undef LOAD_TILE1
#undef STORE_TILE1
#undef MFMA_HALF1

#pragma unroll
  for (int mi = 0; mi < 4; ++mi)
#pragma unroll
    for (int ni = 0; ni < 2; ++ni)
#pragma unroll
      for (int j = 0; j < 4; ++j) {
        int row = m0 + wm * 64 + mi * 16 + fq * 4 + j;
        int col = n0 + wn * 32 + ni * 16 + fr;
        float g = accg[mi][ni][j];
        float u = accu[mi][ni][j];
        float s = g / (1.f + __expf(-g));
        h[(size_t)(e * GT + row) * ID + col] = f2b(s * u);
      }
}

// ---------------------------------------------------------------------------
// Kernel 2 (256x256 tile): out = h @ w2_e   (h bf16, w2 f32, out f32)
// 512 threads = 8 waves (2x4); wave owns 128 rows x 64 cols (acc 128 f32).
// Same mechanics as gemm1-256. LDS = 128 KB.
// ---------------------------------------------------------------------------
__global__ __launch_bounds__(512, 2)
void moe_gemm2(const __bf16* __restrict__ h,
               const float* __restrict__ w2,
               float* __restrict__ out) {
  __shared__ __bf16 As[2][256][BK];
  __shared__ __bf16 Bs[2][256][BK];

  const int t = threadIdx.x;
  const int bid  = blockIdx.x;
  const int work = (bid & 7) * 128 + (bid >> 3);
  const int e    = work >> 5;
  const int rem  = work & 31;
  const int n0   = (rem >> 2) * 256;   // 8 n-tiles, outer
  const int m0   = (rem & 3) * 256;    // 4 m-tiles, inner

  const __bf16* hA = h  + (size_t)(e * GT + m0) * ID;
  const float*  wB = w2 + (size_t)e * ID * HD;

  const int wid = t >> 6, lane = t & 63;
  const int wm = wid >> 2, wn = wid & 3;   // 2x4 waves: 128 rows x 64 cols
  const int fr = lane & 15, fq = lane >> 4;

  const int nq = t & 63;        // n-quad 0..63 (4 cols over 256)
  const int ko = t >> 6;        // k-octet 0..7

  f32x4 acc[8][4];
#pragma unroll
  for (int i = 0; i < 8; ++i)
#pragma unroll
    for (int j = 0; j < 4; ++j) acc[i][j] = 0.f;

  bf16x8 raa[4];
  f32x4 rb[8];

#define LOAD_TILE2(K0)                                                         \
  do {                                                                         \
    _Pragma("unroll")                                                          \
    for (int i = 0; i < 4; ++i) {                                              \
      int id = i * 512 + t;                                                    \
      int koA = id & 7, m = id >> 3;                                           \
      raa[i] = *reinterpret_cast<const bf16x8*>(hA + (size_t)m * ID + (K0) + koA * 8); \
    }                                                                          \
    const float* pg = wB + (size_t)((K0) + ko * 8) * HD + (n0 + nq * 4);       \
    _Pragma("unroll")                                                          \
    for (int j = 0; j < 8; ++j)                                                \
      rb[j] = *reinterpret_cast<const f32x4*>(pg + (size_t)j * HD);            \
  } while (0)

#define STORE_TILE2(P)                                                         \
  do {                                                                         \
    _Pragma("unroll")                                                          \
    for (int i = 0; i < 4; ++i) {                                              \
      int id = i * 512 + t;                                                    \
      int koA = id & 7, m = id >> 3;                                           \
      *reinterpret_cast<bf16x8*>(&As[P][m][(koA ^ (m & 7)) * 8]) = raa[i];     \
    }                                                                          \
    _Pragma("unroll")                                                          \
    for (int c = 0; c < 4; ++c) {                                              \
      int row = nq * 4 + c;                                                    \
      int slot = (ko ^ ((row >> 1) & 7)) * 8;                                  \
      bf16x8 v;                                                                \
      _Pragma("unroll")                                                        \
      for (int j = 0; j < 8; ++j) v[j] = f2b(rb[j][c]);                        \
      *reinterpret_cast<bf16x8*>(&Bs[P][row][slot]) = v;                       \
    }                                                                          \
  } while (0)

#define MFMA_HALF2(P, KB)                                                      \
  do {                                                                         \
    bf16x8 af[8], bf[4];                                                       \
    _Pragma("unroll")                                                          \
    for (int mi = 0; mi < 8; ++mi) {                                           \
      int row = wm * 128 + mi * 16 + fr;                                       \
      int oct = (fq + (KB)) ^ (row & 7);                                       \
      af[mi] = *reinterpret_cast<const bf16x8*>(&As[P][row][oct * 8]);         \
    }                                                                          \
    _Pragma("unroll")                                                          \
    for (int ni = 0; ni < 4; ++ni) {                                           \
      int row = wn * 64 + ni * 16 + fr;                                        \
      int oct = (fq + (KB)) ^ ((row >> 1) & 7);                                \
      bf[ni] = *reinterpret_cast<const bf16x8*>(&Bs[P][row][oct * 8]);         \
    }                                                                          \
    __builtin_amdgcn_s_setprio(1);                                             \
    _Pragma("unroll")                                                          \
    for (int mi = 0; mi < 8; ++mi)                                             \
      _Pragma("unroll")                                                        \
      for (int ni = 0; ni < 4; ++ni)                                           \
        acc[mi][ni] = __builtin_amdgcn_mfma_f32_16x16x32_bf16(                 \
            af[mi], bf[ni], acc[mi][ni], 0, 0, 0);                             \
    __builtin_amdgcn_s_setprio(0);                                             \
  } while (0)

  LOAD_TILE2(0);
  STORE_TILE2(0);
  LOAD_TILE2(BK);
  asm volatile("s_waitcnt lgkmcnt(0)" ::: "memory");
  __builtin_amdgcn_s_barrier();

  for (int k0 = 0, p = 0; k0 < ID; k0 += BK, p ^= 1) {
    MFMA_HALF2(p, 0);
    if (k0 + BK < ID) STORE_TILE2(p ^ 1);
    MFMA_HALF2(p, 4);
    if (k0 + 2 * BK < ID) LOAD_TILE2(k0 + 2 * BK);
    asm volatile("s_waitcnt lgkmcnt(0)" ::: "memory");
    __builtin_amdgcn_s_barrier();
  }
#undef LOAD_TILE2
#undef STORE_TILE2
#undef MFMA_HALF2

#pragma unroll
  for (int mi = 0; mi < 8; ++mi)
#pragma unroll
    for (int ni = 0; ni < 4; ++ni)
#pragma unroll
      for (int j = 0; j < 4; ++j) {
        int row = m0 + wm * 128 + mi * 16 + fq * 4 + j;
        int col = n0 + wn * 64 + ni * 16 + fr;
        out[(size_t)(e * GT + row) * HD + col] = acc[mi][ni][j];
      }
}

extern "C" void kernel_launch(void* const* d_in, const int* in_sizes, int n_in,
                              void* d_out, int out_size, void* d_ws, size_t ws_size,
                              hipStream_t stream) {
  const float* x   = (const float*)d_in[0];
  const float* w13 = (const float*)d_in[1];
  const float* w2  = (const float*)d_in[2];
  float* out = (float*)d_out;

  // ws layout: h [0, 64 MiB) ; x_bf16 [64 MiB, 192 MiB)
  const size_t H_BYTES  = (size_t)GT * NE * ID * sizeof(__bf16);   // 64 MiB
  const size_t XB_BYTES = (size_t)GT * NE * HD * sizeof(__bf16);   // 128 MiB
  __bf16* h  = (__bf16*)d_ws;
  __bf16* xb = (__bf16*)((char*)d_ws + H_BYTES);

  if (ws_size >= H_BYTES + XB_BYTES) {
    cvt_x_bf16<<<dim3((GT * NE * (HD / 8)) / 256), dim3(256), 0, stream>>>(x, xb);
    moe_gemm1_swiglu_bA<<<dim3(1024), dim3(512), 0, stream>>>(xb, w13, h);
  } else {
    moe_gemm1_swiglu<<<dim3(ID / 64, GT / 128, NE), dim3(256), 0, stream>>>(x, w13, h);
  }
  moe_gemm2<<<dim3(1024), dim3(512), 0, stream>>>(h, w2, out);
}